// Round 12
// baseline (232.604 us; speedup 1.0000x reference)
//
#include <hip/hip_runtime.h>
#include <hip/hip_bf16.h>

#define DIMSZ 256
#define HID 4096
#define BATCH 4
#define SEQ 2048
#define NCH 64      // chunks per sequence (carry granularity)
#define CLEN 32     // chunk length
#define SPLITK2 4   // K-splits for fused GEMM2
#define KCHUNK (HID / SPLITK2)   // 1024 channels per block
#define BM2 64      // timesteps per fused-GEMM2 block

typedef __bf16 bf16_t;
typedef __bf16 bf16x8 __attribute__((ext_vector_type(8)));
typedef float  f32x4  __attribute__((ext_vector_type(4)));

__device__ __forceinline__ float sigmoidf_dev(float x) {
    return 1.0f / (1.0f + __expf(-x));
}

// async global->LDS, 16B/lane. LDS dest = wave-uniform base + lane*16.
__device__ __forceinline__ void load_lds16(const bf16_t* g, bf16_t* l) {
    __builtin_amdgcn_global_load_lds(
        (const __attribute__((address_space(1))) void*)g,
        (__attribute__((address_space(3))) void*)l,
        16, 0, 0);
}

__device__ __forceinline__ bf16x8 cvt8(const float* p) {
    bf16x8 o;
    #pragma unroll
    for (int j = 0; j < 8; j++) o[j] = (bf16_t)p[j];
    return o;
}

// ---------------- prep: fused fp32->bf16 convert + MFMA-frag swizzle ----------------
__global__ void prep_kernel(const float* __restrict__ x,
                            const float* __restrict__ WB,
                            const float* __restrict__ WC,
                            bf16_t* __restrict__ xt,
                            bf16_t* __restrict__ WBt,
                            bf16_t* __restrict__ Wt) {
    int i = blockIdx.x * blockDim.x + threadIdx.x;   // 524288
    if (i < 262144) {                                // xt
        int lane = i & 63, m16 = (i >> 6) & 511, ks = i >> 15;
        int row = m16 * 16 + (lane & 15);
        int k   = ks * 32 + (lane >> 4) * 8;
        *(bf16x8*)&xt[(size_t)i * 8] = cvt8(&x[(size_t)row * DIMSZ + k]);
    } else if (i < 393216) {                         // WBt
        int j = i - 262144;
        int lane = j & 63, n16 = (j >> 6) & 255, ks = j >> 14;
        int row = n16 * 16 + (lane & 15);
        int k   = ks * 32 + (lane >> 4) * 8;
        *(bf16x8*)&WBt[(size_t)j * 8] = cvt8(&WB[(size_t)row * DIMSZ + k]);
    } else {                                         // Wt
        int j = i - 393216;
        int lane = j & 63, g = (j >> 6) & 15, ks = j >> 10;
        int row = g * 16 + (lane & 15);
        int k   = ks * 32 + (lane >> 4) * 8;
        *(bf16x8*)&Wt[(size_t)j * 8] = cvt8(&WC[(size_t)row * HID + k]);
    }
}

// ---------------- zero split-K counters ----------------
__global__ void init_counters_kernel(int* __restrict__ counters, int n) {
    int i = blockIdx.x * blockDim.x + threadIdx.x;
    if (i < n) counters[i] = 0;
}

// ---------------- GEMM1 fused: b = x@WB^T + bB (bf16), + per-chunk totals ----------------
__global__ __launch_bounds__(256)
void gemm1_fused(const bf16_t* __restrict__ xt, const bf16_t* __restrict__ WBt,
                 const float* __restrict__ bias, const float* __restrict__ Adecay,
                 bf16_t* __restrict__ Cg, float* __restrict__ totals)
{
    constexpr int N = HID;
    constexpr int LDTILE = 136;
    __shared__ bf16_t tile[128 * LDTILE];   // 34 KB

    const int tid = threadIdx.x, wave = tid >> 6, lane = tid & 63;
    const int wm = wave >> 1, wn = wave & 1, q = lane >> 4, r16 = lane & 15;
    const int mBase = blockIdx.x * 128, nBase = blockIdx.y * 128;
    const int m16Base = blockIdx.x * 8 + wm * 4;
    const int n16Base = blockIdx.y * 8 + wn * 4;

    f32x4 acc[4][4] = {};

    #pragma unroll 2
    for (int ks = 0; ks < 8; ks++) {
        bf16x8 af[4], bfr[4];
        #pragma unroll
        for (int mt = 0; mt < 4; mt++)
            af[mt] = *(const bf16x8*)&xt[(((size_t)ks * 512 + m16Base + mt) * 64 + lane) * 8];
        #pragma unroll
        for (int nt = 0; nt < 4; nt++)
            bfr[nt] = *(const bf16x8*)&WBt[(((size_t)ks * 256 + n16Base + nt) * 64 + lane) * 8];
        #pragma unroll
        for (int mt = 0; mt < 4; mt++)
            #pragma unroll
            for (int nt = 0; nt < 4; nt++)
                acc[mt][nt] = __builtin_amdgcn_mfma_f32_16x16x32_bf16(
                    af[mt], bfr[nt], acc[mt][nt], 0, 0, 0);
    }

    // acc (+bias) -> LDS tile
    #pragma unroll
    for (int nt = 0; nt < 4; nt++) {
        const int chl = wn * 64 + nt * 16 + r16;
        const float bv = bias[nBase + chl];
        #pragma unroll
        for (int mt = 0; mt < 4; mt++) {
            const int t0 = wm * 64 + mt * 16 + q * 4;
            #pragma unroll
            for (int rg = 0; rg < 4; rg++)
                tile[(t0 + rg) * LDTILE + chl] = (bf16_t)(acc[mt][nt][rg] + bv);
        }
    }
    __syncthreads();

    // coalesced writeback: 8 passes x (16 rows x 128 ch)
    #pragma unroll
    for (int p = 0; p < 8; p++) {
        const int t = p * 16 + (tid >> 4);
        const int ch8 = (tid & 15) << 3;
        *(bf16x8*)&Cg[(size_t)(mBase + t) * N + nBase + ch8] =
            *(const bf16x8*)&tile[t * LDTILE + ch8];
    }

    // chunk totals: 128 channels x 4 chunks
    #pragma unroll
    for (int t = 0; t < 2; t++) {
        int task = tid + t * 256;
        int ch = task & 127, ck = task >> 7;
        float a = sigmoidf_dev(Adecay[nBase + ch]);
        float tot = 0.f;
        #pragma unroll 8
        for (int i = 0; i < CLEN; i++)
            tot = a * tot + (float)tile[(ck * CLEN + i) * LDTILE + ch];
        int batch = mBase >> 11;
        int cg = ((mBase & 2047) >> 5) + ck;
        totals[(size_t)(batch * NCH + cg) * HID + nBase + ch] = tot;
    }
}

// ---------------- scan over chunk carries ----------------
__global__ void scan_carries_kernel(const float* __restrict__ totals,
                                    const float* __restrict__ Adecay,
                                    float* __restrict__ carries)
{
    int gid = blockIdx.x * 64 + threadIdx.x;   // BATCH*HID
    int ch    = gid & (HID - 1);
    int batch = gid >> 12;
    float a = sigmoidf_dev(Adecay[ch]);
    float aC = a;
    #pragma unroll
    for (int i = 0; i < 5; i++) aC *= aC;      // a^32
    float carry = 0.f;
    #pragma unroll 8
    for (int c = 0; c < NCH; c++) {
        size_t idx = (size_t)(batch * NCH + c) * HID + ch;
        carries[idx] = carry;
        carry = aC * carry + totals[idx];
    }
}

// ---------------- fused scan + GEMM2 split-K + in-kernel finisher reduction ----------------
__global__ __launch_bounds__(256)
void gemm2_fused(const bf16_t* __restrict__ bv, const bf16_t* __restrict__ Wt,
                 const float* __restrict__ Adecay, const float* __restrict__ carries,
                 const float* __restrict__ totals, float* __restrict__ P,
                 const float* __restrict__ bias, float* __restrict__ outp,
                 int* __restrict__ counters)
{
    constexpr int N = DIMSZ;
    constexpr int CKSTRIDE = BM2 * 32 + 32;    // +64B stagger between ck slabs
    __shared__ bf16_t hs[8 * CKSTRIDE];        // 32.5 KB
    __shared__ int lastFlag;

    const int tid = threadIdx.x, wave = tid >> 6, lane = tid & 63;
    const int q = lane >> 4, r16 = lane & 15;
    const int mBase = blockIdx.x * BM2;
    const int kBase = blockIdx.y * KCHUNK;
    const int batch = mBase >> 11;
    const int chunk0 = (mBase & 2047) >> 5;

    f32x4 acc[4][4] = {};

    for (int s = 0; s < KCHUNK / 256; s++) {
        const int chSlab = kBase + s * 256;

        if (s > 0) __syncthreads();   // all waves done reading hs before DMA lands

        // stage b-slab -> hs
        #pragma unroll
        for (int i = 0; i < 8; i++) {
            int ck = wave * 2 + (i >> 2);
            int g  = i & 3;
            load_lds16(&bv[(size_t)(mBase + g * 16 + (lane >> 2)) * HID
                           + chSlab + ck * 32 + ((lane & 3) << 3)],
                       &hs[ck * CKSTRIDE + g * 512]);
        }

        // seeds (independent coalesced loads, issued during staging)
        const int ck = tid >> 5, ch = tid & 31;
        const int c = chSlab + ck * 32 + ch;
        const float a = sigmoidf_dev(Adecay[c]);
        float aC = a;
        #pragma unroll
        for (int i = 0; i < 5; i++) aC *= aC;  // a^32
        const size_t seedIdx = (size_t)(batch * NCH + chunk0) * HID + c;
        const float carry0 = carries[seedIdx];
        const float carry1 = aC * carry0 + totals[seedIdx];

        __syncthreads();   // staging drained

        // in-place scan: 2 independent 32-step chains
        {
            bf16_t* hp = &hs[ck * CKSTRIDE + ch];
            float st0 = carry0, st1 = carry1;
            #pragma unroll 8
            for (int t = 0; t < 32; t++) {
                st0 = a * st0 + (float)hp[t * 32];
                st1 = a * st1 + (float)hp[(t + 32) * 32];
                hp[t * 32]        = (bf16_t)st0;
                hp[(t + 32) * 32] = (bf16_t)st1;
            }
        }
        __syncthreads();   // hs = h, visible to all waves

        // barrier-free MFMA k-steps; B-frags direct from swizzled global
        const int ksBase = (kBase >> 5) + s * 8;
        #pragma unroll 2
        for (int cki = 0; cki < 8; cki++) {
            bf16x8 af[4], bfr[4];
            #pragma unroll
            for (int nt = 0; nt < 4; nt++)
                bfr[nt] = *(const bf16x8*)&Wt[
                    (((size_t)(ksBase + cki) * 16 + wave * 4 + nt) * 64 + lane) * 8];
            #pragma unroll
            for (int mt = 0; mt < 4; mt++)
                af[mt] = *(const bf16x8*)&hs[cki * CKSTRIDE + (mt * 16 + r16) * 32 + q * 8];
            #pragma unroll
            for (int mt = 0; mt < 4; mt++)
                #pragma unroll
                for (int nt = 0; nt < 4; nt++)
                    acc[mt][nt] = __builtin_amdgcn_mfma_f32_16x16x32_bf16(
                        af[mt], bfr[nt], acc[mt][nt], 0, 0, 0);
        }
    }

    // epilogue: fp32 partials
    float* Pb = P + (size_t)blockIdx.y * (BATCH * SEQ) * N;
    #pragma unroll
    for (int nt = 0; nt < 4; nt++) {
        const int col = wave * 64 + nt * 16 + r16;
        #pragma unroll
        for (int mt = 0; mt < 4; mt++) {
            const int row0 = mBase + mt * 16 + q * 4;
            #pragma unroll
            for (int rg = 0; rg < 4; rg++)
                Pb[(size_t)(row0 + rg) * N + col] = acc[mt][nt][rg];
        }
    }

    // split-K finisher: last-arriving split for this m-block sums partials + bias.
    // Writers: fence (writeback partials to LLC) then device-scope atomic bump.
    __threadfence();
    if (tid == 0)
        lastFlag = (atomicAdd(&counters[blockIdx.x], 1) == SPLITK2 - 1);
    __syncthreads();
    if (lastFlag) {
        __threadfence();   // acquire side: see all splits' partials
        const float4* b4 = (const float4*)bias;
        const float4* P4 = (const float4*)P;
        float4* o4 = (float4*)outp;
        constexpr int NW = DIMSZ / 4;               // 64 float4/row
        #pragma unroll 4
        for (int i = tid; i < BM2 * NW; i += 256) {
            int r = i >> 6, c4 = i & 63;
            size_t rowOff = (size_t)(mBase + r) * NW + c4;
            float4 v = b4[c4];
            #pragma unroll
            for (int sp = 0; sp < SPLITK2; sp++) {
                float4 p = P4[(size_t)sp * (BATCH * SEQ) * NW + rowOff];
                v.x += p.x; v.y += p.y; v.z += p.z; v.w += p.w;
            }
            o4[rowOff] = v;
        }
    }
}

extern "C" void kernel_launch(void* const* d_in, const int* in_sizes, int n_in,
                              void* d_out, int out_size, void* d_ws, size_t ws_size,
                              hipStream_t stream)
{
    const float* x  = (const float*)d_in[0];
    const float* WB = (const float*)d_in[1];
    const float* bB = (const float*)d_in[2];
    const float* WC = (const float*)d_in[3];
    const float* bC = (const float*)d_in[4];
    const float* A  = (const float*)d_in[5];

    char* ws = (char*)d_ws;
    size_t off = 0;
    bf16_t* xt   = (bf16_t*)(ws + off); off += (size_t)BATCH * SEQ * DIMSZ * 2;  // 4 MB
    bf16_t* WBt  = (bf16_t*)(ws + off); off += (size_t)HID * DIMSZ * 2;          // 2 MB
    bf16_t* Wt   = (bf16_t*)(ws + off); off += (size_t)DIMSZ * HID * 2;          // 2 MB
    bf16_t* bbuf = (bf16_t*)(ws + off); off += (size_t)BATCH * SEQ * HID * 2;    // 64 MB
    float* partials = (float*)(ws + off); off += (size_t)SPLITK2 * BATCH * SEQ * DIMSZ * 4;
    float* totals   = (float*)(ws + off); off += (size_t)BATCH * NCH * HID * 4;
    float* carries  = (float*)(ws + off); off += (size_t)BATCH * NCH * HID * 4;
    int* counters   = (int*)(ws + off);  off += 128 * sizeof(int);

    const int M = BATCH * SEQ;   // 8192

    prep_kernel<<<2048, 256, 0, stream>>>(x, WB, WC, xt, WBt, Wt);
    init_counters_kernel<<<1, 128, 0, stream>>>(counters, 128);

    dim3 g1(M / 128, HID / 128);
    gemm1_fused<<<g1, 256, 0, stream>>>(xt, WBt, bB, A, bbuf, totals);

    scan_carries_kernel<<<256, 64, 0, stream>>>(totals, A, carries);

    dim3 g2(M / BM2, SPLITK2);
    gemm2_fused<<<g2, 256, 0, stream>>>(bbuf, Wt, A, carries, totals, partials,
                                        bC, (float*)d_out, counters);
}

// Round 13
// 149.852 us; speedup vs baseline: 1.5522x; 1.5522x over previous
//
#include <hip/hip_runtime.h>
#include <hip/hip_bf16.h>

#define DIMSZ 256
#define HID 4096
#define BATCH 4
#define SEQ 2048
#define NCH 64      // chunks per sequence (carry granularity)
#define CLEN 32     // chunk length
#define SPLITK2 4   // K-splits for fused GEMM2
#define KCHUNK (HID / SPLITK2)   // 1024 channels per block
#define BM2 32      // timesteps per fused-GEMM2 block (= 1 chunk)

typedef __bf16 bf16_t;
typedef __bf16 bf16x8 __attribute__((ext_vector_type(8)));
typedef float  f32x4  __attribute__((ext_vector_type(4)));

__device__ __forceinline__ float sigmoidf_dev(float x) {
    return 1.0f / (1.0f + __expf(-x));
}

// async global->LDS, 16B/lane. LDS dest = wave-uniform base + lane*16.
__device__ __forceinline__ void load_lds16(const bf16_t* g, bf16_t* l) {
    __builtin_amdgcn_global_load_lds(
        (const __attribute__((address_space(1))) void*)g,
        (__attribute__((address_space(3))) void*)l,
        16, 0, 0);
}

__device__ __forceinline__ bf16x8 cvt8(const float* p) {
    bf16x8 o;
    #pragma unroll
    for (int j = 0; j < 8; j++) o[j] = (bf16_t)p[j];
    return o;
}

// ---------------- prep: fused fp32->bf16 convert + MFMA-frag swizzle ----------------
__global__ void prep_kernel(const float* __restrict__ x,
                            const float* __restrict__ WB,
                            const float* __restrict__ WC,
                            bf16_t* __restrict__ xt,
                            bf16_t* __restrict__ WBt,
                            bf16_t* __restrict__ Wt) {
    int i = blockIdx.x * blockDim.x + threadIdx.x;   // 524288
    if (i < 262144) {                                // xt
        int lane = i & 63, m16 = (i >> 6) & 511, ks = i >> 15;
        int row = m16 * 16 + (lane & 15);
        int k   = ks * 32 + (lane >> 4) * 8;
        *(bf16x8*)&xt[(size_t)i * 8] = cvt8(&x[(size_t)row * DIMSZ + k]);
    } else if (i < 393216) {                         // WBt
        int j = i - 262144;
        int lane = j & 63, n16 = (j >> 6) & 255, ks = j >> 14;
        int row = n16 * 16 + (lane & 15);
        int k   = ks * 32 + (lane >> 4) * 8;
        *(bf16x8*)&WBt[(size_t)j * 8] = cvt8(&WB[(size_t)row * DIMSZ + k]);
    } else {                                         // Wt
        int j = i - 393216;
        int lane = j & 63, g = (j >> 6) & 15, ks = j >> 10;
        int row = g * 16 + (lane & 15);
        int k   = ks * 32 + (lane >> 4) * 8;
        *(bf16x8*)&Wt[(size_t)j * 8] = cvt8(&WC[(size_t)row * HID + k]);
    }
}

// ---------------- GEMM1 fused: b = x@WB^T + bB (bf16), + per-chunk totals ----------------
__global__ __launch_bounds__(256)
void gemm1_fused(const bf16_t* __restrict__ xt, const bf16_t* __restrict__ WBt,
                 const float* __restrict__ bias, const float* __restrict__ Adecay,
                 bf16_t* __restrict__ Cg, float* __restrict__ totals)
{
    constexpr int N = HID;
    constexpr int LDTILE = 136;
    __shared__ bf16_t tile[128 * LDTILE];   // 34 KB

    const int tid = threadIdx.x, wave = tid >> 6, lane = tid & 63;
    const int wm = wave >> 1, wn = wave & 1, q = lane >> 4, r16 = lane & 15;
    const int mBase = blockIdx.x * 128, nBase = blockIdx.y * 128;
    const int m16Base = blockIdx.x * 8 + wm * 4;
    const int n16Base = blockIdx.y * 8 + wn * 4;

    f32x4 acc[4][4] = {};

    #pragma unroll 2
    for (int ks = 0; ks < 8; ks++) {
        bf16x8 af[4], bfr[4];
        #pragma unroll
        for (int mt = 0; mt < 4; mt++)
            af[mt] = *(const bf16x8*)&xt[(((size_t)ks * 512 + m16Base + mt) * 64 + lane) * 8];
        #pragma unroll
        for (int nt = 0; nt < 4; nt++)
            bfr[nt] = *(const bf16x8*)&WBt[(((size_t)ks * 256 + n16Base + nt) * 64 + lane) * 8];
        #pragma unroll
        for (int mt = 0; mt < 4; mt++)
            #pragma unroll
            for (int nt = 0; nt < 4; nt++)
                acc[mt][nt] = __builtin_amdgcn_mfma_f32_16x16x32_bf16(
                    af[mt], bfr[nt], acc[mt][nt], 0, 0, 0);
    }

    // acc (+bias) -> LDS tile
    #pragma unroll
    for (int nt = 0; nt < 4; nt++) {
        const int chl = wn * 64 + nt * 16 + r16;
        const float bv = bias[nBase + chl];
        #pragma unroll
        for (int mt = 0; mt < 4; mt++) {
            const int t0 = wm * 64 + mt * 16 + q * 4;
            #pragma unroll
            for (int rg = 0; rg < 4; rg++)
                tile[(t0 + rg) * LDTILE + chl] = (bf16_t)(acc[mt][nt][rg] + bv);
        }
    }
    __syncthreads();

    // coalesced writeback: 8 passes x (16 rows x 128 ch)
    #pragma unroll
    for (int p = 0; p < 8; p++) {
        const int t = p * 16 + (tid >> 4);
        const int ch8 = (tid & 15) << 3;
        *(bf16x8*)&Cg[(size_t)(mBase + t) * N + nBase + ch8] =
            *(const bf16x8*)&tile[t * LDTILE + ch8];
    }

    // chunk totals: 128 channels x 4 chunks
    #pragma unroll
    for (int t = 0; t < 2; t++) {
        int task = tid + t * 256;
        int ch = task & 127, ck = task >> 7;
        float a = sigmoidf_dev(Adecay[nBase + ch]);
        float tot = 0.f;
        #pragma unroll 8
        for (int i = 0; i < CLEN; i++)
            tot = a * tot + (float)tile[(ck * CLEN + i) * LDTILE + ch];
        int batch = mBase >> 11;
        int cg = ((mBase & 2047) >> 5) + ck;
        totals[(size_t)(batch * NCH + cg) * HID + nBase + ch] = tot;
    }
}

// ---------------- scan over chunk carries ----------------
__global__ void scan_carries_kernel(const float* __restrict__ totals,
                                    const float* __restrict__ Adecay,
                                    float* __restrict__ carries)
{
    int gid = blockIdx.x * 64 + threadIdx.x;   // BATCH*HID
    int ch    = gid & (HID - 1);
    int batch = gid >> 12;
    float a = sigmoidf_dev(Adecay[ch]);
    float aC = a;
    #pragma unroll
    for (int i = 0; i < 5; i++) aC *= aC;      // a^32
    float carry = 0.f;
    #pragma unroll 8
    for (int c = 0; c < NCH; c++) {
        size_t idx = (size_t)(batch * NCH + c) * HID + ch;
        carries[idx] = carry;
        carry = aC * carry + totals[idx];
    }
}

// ---------------- fused scan + GEMM2 split-K (BM2=32, bf16 partials) ----------------
// Per block: 32 timesteps (= 1 chunk) x N=256 x 1024-ch K-slice, 4 slabs of 256 ch.
// hs (16.9 KB) doubles as the bf16 epilogue tile after the last slab.
__global__ __launch_bounds__(256)
void gemm2_fused(const bf16_t* __restrict__ bv, const bf16_t* __restrict__ Wt,
                 const float* __restrict__ Adecay, const float* __restrict__ carries,
                 bf16_t* __restrict__ P)
{
    constexpr int CKSTRIDE = BM2 * 32 + 32;    // 1056: +64B stagger between ck slabs
    __shared__ bf16_t hs[8 * CKSTRIDE];        // 16.9 KB (== 32x264 epilogue tile)

    const int tid = threadIdx.x, wave = tid >> 6, lane = tid & 63;
    const int q = lane >> 4, r16 = lane & 15;
    const int mBase = blockIdx.x * BM2;
    const int kBase = blockIdx.y * KCHUNK;
    const int batch = mBase >> 11;
    const int chunk0 = (mBase & 2047) >> 5;

    f32x4 acc[2][4] = {};

    for (int s = 0; s < KCHUNK / 256; s++) {
        const int chSlab = kBase + s * 256;

        if (s > 0) __syncthreads();   // all waves done reading hs before DMA lands

        // stage b-slab -> hs: 16 wave-loads total, 4 per wave
        #pragma unroll
        for (int i = 0; i < 4; i++) {
            int ck = wave * 2 + (i >> 1);
            int g  = i & 1;
            load_lds16(&bv[(size_t)(mBase + g * 16 + (lane >> 2)) * HID
                           + chSlab + ck * 32 + ((lane & 3) << 3)],
                       &hs[ck * CKSTRIDE + g * 512]);
        }

        // seed (coalesced load, issued during staging)
        const int ck = tid >> 5, ch = tid & 31;
        const int c = chSlab + ck * 32 + ch;
        const float a = sigmoidf_dev(Adecay[c]);
        float st = carries[(size_t)(batch * NCH + chunk0) * HID + c];

        __syncthreads();   // staging drained

        // in-place scan: single 32-step chain (block = exactly one chunk)
        {
            bf16_t* hp = &hs[ck * CKSTRIDE + ch];
            #pragma unroll 8
            for (int t = 0; t < BM2; t++) {
                st = a * st + (float)hp[t * 32];
                hp[t * 32] = (bf16_t)st;
            }
        }
        __syncthreads();   // hs = h, visible to all waves

        // barrier-free MFMA k-steps; B-frags direct from swizzled global
        const int ksBase = (kBase >> 5) + s * 8;
        #pragma unroll 2
        for (int cki = 0; cki < 8; cki++) {
            bf16x8 af[2], bfr[4];
            #pragma unroll
            for (int nt = 0; nt < 4; nt++)
                bfr[nt] = *(const bf16x8*)&Wt[
                    (((size_t)(ksBase + cki) * 16 + wave * 4 + nt) * 64 + lane) * 8];
            #pragma unroll
            for (int mt = 0; mt < 2; mt++)
                af[mt] = *(const bf16x8*)&hs[cki * CKSTRIDE + (mt * 16 + r16) * 32 + q * 8];
            #pragma unroll
            for (int mt = 0; mt < 2; mt++)
                #pragma unroll
                for (int nt = 0; nt < 4; nt++)
                    acc[mt][nt] = __builtin_amdgcn_mfma_f32_16x16x32_bf16(
                        af[mt], bfr[nt], acc[mt][nt], 0, 0, 0);
        }
    }

    // epilogue: acc -> bf16 LDS tile (reuse hs) -> coalesced 16B partial stores
    __syncthreads();                           // all waves done reading hs
    #pragma unroll
    for (int nt = 0; nt < 4; nt++) {
        const int col = wave * 64 + nt * 16 + r16;
        #pragma unroll
        for (int mt = 0; mt < 2; mt++)
            #pragma unroll
            for (int rg = 0; rg < 4; rg++)
                hs[(mt * 16 + q * 4 + rg) * 264 + col] = (bf16_t)acc[mt][nt][rg];
    }
    __syncthreads();

    bf16_t* Pb = P + (size_t)blockIdx.y * (BATCH * SEQ) * DIMSZ;
    #pragma unroll
    for (int p = 0; p < 4; p++) {
        int task = p * 256 + tid;
        int r = task >> 5, g8 = (task & 31) << 3;
        *(bf16x8*)&Pb[(size_t)(mBase + r) * DIMSZ + g8] =
            *(const bf16x8*)&hs[r * 264 + g8];
    }
}

// ---------------- reduce bf16 partials + bias -> fp32 d_out ----------------
__global__ void reduce_out_kernel(const bf16_t* __restrict__ P,
                                  const float* __restrict__ bias,
                                  float* __restrict__ out, int nTask) {
    int i = blockIdx.x * blockDim.x + threadIdx.x;   // M*256/8
    if (i >= nTask) return;
    int n8 = (i & 31) << 3;
    size_t off = (size_t)i * 8;
    float v[8];
    #pragma unroll
    for (int j = 0; j < 8; j++) v[j] = bias[n8 + j];
    #pragma unroll
    for (int sp = 0; sp < SPLITK2; sp++) {
        bf16x8 p = *(const bf16x8*)&P[(size_t)sp * (BATCH * SEQ) * DIMSZ + off];
        #pragma unroll
        for (int j = 0; j < 8; j++) v[j] += (float)p[j];
    }
    float4* o4 = (float4*)&out[off];
    o4[0] = make_float4(v[0], v[1], v[2], v[3]);
    o4[1] = make_float4(v[4], v[5], v[6], v[7]);
}

extern "C" void kernel_launch(void* const* d_in, const int* in_sizes, int n_in,
                              void* d_out, int out_size, void* d_ws, size_t ws_size,
                              hipStream_t stream)
{
    const float* x  = (const float*)d_in[0];
    const float* WB = (const float*)d_in[1];
    const float* bB = (const float*)d_in[2];
    const float* WC = (const float*)d_in[3];
    const float* bC = (const float*)d_in[4];
    const float* A  = (const float*)d_in[5];

    char* ws = (char*)d_ws;
    size_t off = 0;
    bf16_t* xt   = (bf16_t*)(ws + off); off += (size_t)BATCH * SEQ * DIMSZ * 2;  // 4 MB
    bf16_t* WBt  = (bf16_t*)(ws + off); off += (size_t)HID * DIMSZ * 2;          // 2 MB
    bf16_t* Wt   = (bf16_t*)(ws + off); off += (size_t)DIMSZ * HID * 2;          // 2 MB
    bf16_t* bbuf = (bf16_t*)(ws + off); off += (size_t)BATCH * SEQ * HID * 2;    // 64 MB
    bf16_t* partials = (bf16_t*)(ws + off); off += (size_t)SPLITK2 * BATCH * SEQ * DIMSZ * 2; // 16.75 MB
    float* totals   = (float*)(ws + off); off += (size_t)BATCH * NCH * HID * 4;
    float* carries  = (float*)(ws + off); off += (size_t)BATCH * NCH * HID * 4;

    const int M = BATCH * SEQ;   // 8192

    prep_kernel<<<2048, 256, 0, stream>>>(x, WB, WC, xt, WBt, Wt);

    dim3 g1(M / 128, HID / 128);
    gemm1_fused<<<g1, 256, 0, stream>>>(xt, WBt, bB, A, bbuf, totals);

    scan_carries_kernel<<<256, 64, 0, stream>>>(totals, A, carries);

    dim3 g2(M / BM2, SPLITK2);
    gemm2_fused<<<g2, 256, 0, stream>>>(bbuf, Wt, A, carries, partials);

    int nTask = M * DIMSZ / 8;
    reduce_out_kernel<<<(nTask + 255) / 256, 256, 0, stream>>>(
        partials, bC, (float*)d_out, nTask);
}

// Round 14
// 147.374 us; speedup vs baseline: 1.5783x; 1.0168x over previous
//
#include <hip/hip_runtime.h>
#include <hip/hip_bf16.h>

#define DIMSZ 256
#define HID 4096
#define BATCH 4
#define SEQ 2048
#define NCH 64      // chunks per sequence (carry granularity)
#define CLEN 32     // chunk length
#define SPLITK2 4   // K-splits for fused GEMM2
#define KCHUNK (HID / SPLITK2)   // 1024 channels per block
#define BM2 32      // timesteps per fused-GEMM2 block (= 1 chunk)

typedef __bf16 bf16_t;
typedef __bf16 bf16x8 __attribute__((ext_vector_type(8)));
typedef float  f32x4  __attribute__((ext_vector_type(4)));

__device__ __forceinline__ float sigmoidf_dev(float x) {
    return 1.0f / (1.0f + __expf(-x));
}

// async global->LDS, 16B/lane. LDS dest = wave-uniform base + lane*16.
__device__ __forceinline__ void load_lds16(const bf16_t* g, bf16_t* l) {
    __builtin_amdgcn_global_load_lds(
        (const __attribute__((address_space(1))) void*)g,
        (__attribute__((address_space(3))) void*)l,
        16, 0, 0);
}

__device__ __forceinline__ bf16x8 cvt8(const float* p) {
    bf16x8 o;
    #pragma unroll
    for (int j = 0; j < 8; j++) o[j] = (bf16_t)p[j];
    return o;
}

// ---------------- prep: fused fp32->bf16 convert + MFMA-frag swizzle ----------------
__global__ void prep_kernel(const float* __restrict__ x,
                            const float* __restrict__ WB,
                            const float* __restrict__ WC,
                            bf16_t* __restrict__ xt,
                            bf16_t* __restrict__ WBt,
                            bf16_t* __restrict__ Wt) {
    int i = blockIdx.x * blockDim.x + threadIdx.x;   // 524288
    if (i < 262144) {                                // xt
        int lane = i & 63, m16 = (i >> 6) & 511, ks = i >> 15;
        int row = m16 * 16 + (lane & 15);
        int k   = ks * 32 + (lane >> 4) * 8;
        *(bf16x8*)&xt[(size_t)i * 8] = cvt8(&x[(size_t)row * DIMSZ + k]);
    } else if (i < 393216) {                         // WBt
        int j = i - 262144;
        int lane = j & 63, n16 = (j >> 6) & 255, ks = j >> 14;
        int row = n16 * 16 + (lane & 15);
        int k   = ks * 32 + (lane >> 4) * 8;
        *(bf16x8*)&WBt[(size_t)j * 8] = cvt8(&WB[(size_t)row * DIMSZ + k]);
    } else {                                         // Wt
        int j = i - 393216;
        int lane = j & 63, g = (j >> 6) & 15, ks = j >> 10;
        int row = g * 16 + (lane & 15);
        int k   = ks * 32 + (lane >> 4) * 8;
        *(bf16x8*)&Wt[(size_t)j * 8] = cvt8(&WC[(size_t)row * HID + k]);
    }
}

// ---------------- GEMM1 fused: b = x@WB^T + bB (bf16), + per-chunk totals ----------------
__global__ __launch_bounds__(256)
void gemm1_fused(const bf16_t* __restrict__ xt, const bf16_t* __restrict__ WBt,
                 const float* __restrict__ bias, const float* __restrict__ Adecay,
                 bf16_t* __restrict__ Cg, float* __restrict__ totals)
{
    constexpr int N = HID;
    constexpr int LDTILE = 136;
    __shared__ bf16_t tile[128 * LDTILE];   // 34 KB

    const int tid = threadIdx.x, wave = tid >> 6, lane = tid & 63;
    const int wm = wave >> 1, wn = wave & 1, q = lane >> 4, r16 = lane & 15;
    const int mBase = blockIdx.x * 128, nBase = blockIdx.y * 128;
    const int m16Base = blockIdx.x * 8 + wm * 4;
    const int n16Base = blockIdx.y * 8 + wn * 4;

    f32x4 acc[4][4] = {};

    #pragma unroll 2
    for (int ks = 0; ks < 8; ks++) {
        bf16x8 af[4], bfr[4];
        #pragma unroll
        for (int mt = 0; mt < 4; mt++)
            af[mt] = *(const bf16x8*)&xt[(((size_t)ks * 512 + m16Base + mt) * 64 + lane) * 8];
        #pragma unroll
        for (int nt = 0; nt < 4; nt++)
            bfr[nt] = *(const bf16x8*)&WBt[(((size_t)ks * 256 + n16Base + nt) * 64 + lane) * 8];
        #pragma unroll
        for (int mt = 0; mt < 4; mt++)
            #pragma unroll
            for (int nt = 0; nt < 4; nt++)
                acc[mt][nt] = __builtin_amdgcn_mfma_f32_16x16x32_bf16(
                    af[mt], bfr[nt], acc[mt][nt], 0, 0, 0);
    }

    // acc (+bias) -> LDS tile
    #pragma unroll
    for (int nt = 0; nt < 4; nt++) {
        const int chl = wn * 64 + nt * 16 + r16;
        const float bv = bias[nBase + chl];
        #pragma unroll
        for (int mt = 0; mt < 4; mt++) {
            const int t0 = wm * 64 + mt * 16 + q * 4;
            #pragma unroll
            for (int rg = 0; rg < 4; rg++)
                tile[(t0 + rg) * LDTILE + chl] = (bf16_t)(acc[mt][nt][rg] + bv);
        }
    }
    __syncthreads();

    // coalesced writeback: 8 passes x (16 rows x 128 ch)
    #pragma unroll
    for (int p = 0; p < 8; p++) {
        const int t = p * 16 + (tid >> 4);
        const int ch8 = (tid & 15) << 3;
        *(bf16x8*)&Cg[(size_t)(mBase + t) * N + nBase + ch8] =
            *(const bf16x8*)&tile[t * LDTILE + ch8];
    }

    // chunk totals: 128 channels x 4 chunks. Register-batched: issue all 32
    // independent LDS reads first (pipelined), THEN the serial fma chain —
    // avoids chaining each 120-cyc ds_read behind the previous fma.
    #pragma unroll
    for (int t = 0; t < 2; t++) {
        int task = tid + t * 256;
        int ch = task & 127, ck = task >> 7;
        float a = sigmoidf_dev(Adecay[nBase + ch]);
        float v[CLEN];
        #pragma unroll
        for (int i = 0; i < CLEN; i++)
            v[i] = (float)tile[(ck * CLEN + i) * LDTILE + ch];
        float tot = 0.f;
        #pragma unroll
        for (int i = 0; i < CLEN; i++)
            tot = a * tot + v[i];
        int batch = mBase >> 11;
        int cg = ((mBase & 2047) >> 5) + ck;
        totals[(size_t)(batch * NCH + cg) * HID + nBase + ch] = tot;
    }
}

// ---------------- scan over chunk carries ----------------
__global__ void scan_carries_kernel(const float* __restrict__ totals,
                                    const float* __restrict__ Adecay,
                                    float* __restrict__ carries)
{
    int gid = blockIdx.x * 64 + threadIdx.x;   // BATCH*HID
    int ch    = gid & (HID - 1);
    int batch = gid >> 12;
    float a = sigmoidf_dev(Adecay[ch]);
    float aC = a;
    #pragma unroll
    for (int i = 0; i < 5; i++) aC *= aC;      // a^32
    float carry = 0.f;
    #pragma unroll 8
    for (int c = 0; c < NCH; c++) {
        size_t idx = (size_t)(batch * NCH + c) * HID + ch;
        carries[idx] = carry;
        carry = aC * carry + totals[idx];
    }
}

// ---------------- fused scan + GEMM2 split-K (BM2=32, bf16 partials) ----------------
// Per block: 32 timesteps (= 1 chunk) x N=256 x 1024-ch K-slice, 4 slabs of 256 ch.
// hs (16.9 KB) doubles as the bf16 epilogue tile after the last slab.
__global__ __launch_bounds__(256)
void gemm2_fused(const bf16_t* __restrict__ bv, const bf16_t* __restrict__ Wt,
                 const float* __restrict__ Adecay, const float* __restrict__ carries,
                 bf16_t* __restrict__ P)
{
    constexpr int CKSTRIDE = BM2 * 32 + 32;    // 1056: +64B stagger between ck slabs
    __shared__ bf16_t hs[8 * CKSTRIDE];        // 16.9 KB (== 32x264 epilogue tile)

    const int tid = threadIdx.x, wave = tid >> 6, lane = tid & 63;
    const int q = lane >> 4, r16 = lane & 15;
    const int mBase = blockIdx.x * BM2;
    const int kBase = blockIdx.y * KCHUNK;
    const int batch = mBase >> 11;
    const int chunk0 = (mBase & 2047) >> 5;

    f32x4 acc[2][4] = {};

    for (int s = 0; s < KCHUNK / 256; s++) {
        const int chSlab = kBase + s * 256;

        if (s > 0) __syncthreads();   // all waves done reading hs before DMA lands

        // stage b-slab -> hs: 16 wave-loads total, 4 per wave
        #pragma unroll
        for (int i = 0; i < 4; i++) {
            int ck = wave * 2 + (i >> 1);
            int g  = i & 1;
            load_lds16(&bv[(size_t)(mBase + g * 16 + (lane >> 2)) * HID
                           + chSlab + ck * 32 + ((lane & 3) << 3)],
                       &hs[ck * CKSTRIDE + g * 512]);
        }

        // seed (coalesced load, issued during staging)
        const int ck = tid >> 5, ch = tid & 31;
        const int c = chSlab + ck * 32 + ch;
        const float a = sigmoidf_dev(Adecay[c]);
        float st = carries[(size_t)(batch * NCH + chunk0) * HID + c];

        __syncthreads();   // staging drained

        // in-place scan, register-batched: 32 independent ds_reads issued up
        // front (pipelined ~500 cyc), serial fma chain in registers (~128 cyc),
        // then 32 stores — vs interleaved read/fma/write chaining a 120-cyc
        // LDS latency into every step (~4200 cyc/slab).
        {
            bf16_t* hp = &hs[ck * CKSTRIDE + ch];
            float v[BM2];
            #pragma unroll
            for (int t = 0; t < BM2; t++)
                v[t] = (float)hp[t * 32];
            #pragma unroll
            for (int t = 0; t < BM2; t++) {
                st = a * st + v[t];
                v[t] = st;
            }
            #pragma unroll
            for (int t = 0; t < BM2; t++)
                hp[t * 32] = (bf16_t)v[t];
        }
        __syncthreads();   // hs = h, visible to all waves

        // barrier-free MFMA k-steps; B-frags direct from swizzled global
        const int ksBase = (kBase >> 5) + s * 8;
        #pragma unroll 2
        for (int cki = 0; cki < 8; cki++) {
            bf16x8 af[2], bfr[4];
            #pragma unroll
            for (int nt = 0; nt < 4; nt++)
                bfr[nt] = *(const bf16x8*)&Wt[
                    (((size_t)(ksBase + cki) * 16 + wave * 4 + nt) * 64 + lane) * 8];
            #pragma unroll
            for (int mt = 0; mt < 2; mt++)
                af[mt] = *(const bf16x8*)&hs[cki * CKSTRIDE + (mt * 16 + r16) * 32 + q * 8];
            #pragma unroll
            for (int mt = 0; mt < 2; mt++)
                #pragma unroll
                for (int nt = 0; nt < 4; nt++)
                    acc[mt][nt] = __builtin_amdgcn_mfma_f32_16x16x32_bf16(
                        af[mt], bfr[nt], acc[mt][nt], 0, 0, 0);
        }
    }

    // epilogue: acc -> bf16 LDS tile (reuse hs) -> coalesced 16B partial stores
    __syncthreads();                           // all waves done reading hs
    #pragma unroll
    for (int nt = 0; nt < 4; nt++) {
        const int col = wave * 64 + nt * 16 + r16;
        #pragma unroll
        for (int mt = 0; mt < 2; mt++)
            #pragma unroll
            for (int rg = 0; rg < 4; rg++)
                hs[(mt * 16 + q * 4 + rg) * 264 + col] = (bf16_t)acc[mt][nt][rg];
    }
    __syncthreads();

    bf16_t* Pb = P + (size_t)blockIdx.y * (BATCH * SEQ) * DIMSZ;
    #pragma unroll
    for (int p = 0; p < 4; p++) {
        int task = p * 256 + tid;
        int r = task >> 5, g8 = (task & 31) << 3;
        *(bf16x8*)&Pb[(size_t)(mBase + r) * DIMSZ + g8] =
            *(const bf16x8*)&hs[r * 264 + g8];
    }
}

// ---------------- reduce bf16 partials + bias -> fp32 d_out ----------------
__global__ void reduce_out_kernel(const bf16_t* __restrict__ P,
                                  const float* __restrict__ bias,
                                  float* __restrict__ out, int nTask) {
    int i = blockIdx.x * blockDim.x + threadIdx.x;   // M*256/8
    if (i >= nTask) return;
    int n8 = (i & 31) << 3;
    size_t off = (size_t)i * 8;
    float v[8];
    #pragma unroll
    for (int j = 0; j < 8; j++) v[j] = bias[n8 + j];
    #pragma unroll
    for (int sp = 0; sp < SPLITK2; sp++) {
        bf16x8 p = *(const bf16x8*)&P[(size_t)sp * (BATCH * SEQ) * DIMSZ + off];
        #pragma unroll
        for (int j = 0; j < 8; j++) v[j] += (float)p[j];
    }
    float4* o4 = (float4*)&out[off];
    o4[0] = make_float4(v[0], v[1], v[2], v[3]);
    o4[1] = make_float4(v[4], v[5], v[6], v[7]);
}

extern "C" void kernel_launch(void* const* d_in, const int* in_sizes, int n_in,
                              void* d_out, int out_size, void* d_ws, size_t ws_size,
                              hipStream_t stream)
{
    const float* x  = (const float*)d_in[0];
    const float* WB = (const float*)d_in[1];
    const float* bB = (const float*)d_in[2];
    const float* WC = (const float*)d_in[3];
    const float* bC = (const float*)d_in[4];
    const float* A  = (const float*)d_in[5];

    char* ws = (char*)d_ws;
    size_t off = 0;
    bf16_t* xt   = (bf16_t*)(ws + off); off += (size_t)BATCH * SEQ * DIMSZ * 2;  // 4 MB
    bf16_t* WBt  = (bf16_t*)(ws + off); off += (size_t)HID * DIMSZ * 2;          // 2 MB
    bf16_t* Wt   = (bf16_t*)(ws + off); off += (size_t)DIMSZ * HID * 2;          // 2 MB
    bf16_t* bbuf = (bf16_t*)(ws + off); off += (size_t)BATCH * SEQ * HID * 2;    // 64 MB
    bf16_t* partials = (bf16_t*)(ws + off); off += (size_t)SPLITK2 * BATCH * SEQ * DIMSZ * 2; // 16.75 MB
    float* totals   = (float*)(ws + off); off += (size_t)BATCH * NCH * HID * 4;
    float* carries  = (float*)(ws + off); off += (size_t)BATCH * NCH * HID * 4;

    const int M = BATCH * SEQ;   // 8192

    prep_kernel<<<2048, 256, 0, stream>>>(x, WB, WC, xt, WBt, Wt);

    dim3 g1(M / 128, HID / 128);
    gemm1_fused<<<g1, 256, 0, stream>>>(xt, WBt, bB, A, bbuf, totals);

    scan_carries_kernel<<<256, 64, 0, stream>>>(totals, A, carries);

    dim3 g2(M / BM2, SPLITK2);
    gemm2_fused<<<g2, 256, 0, stream>>>(bbuf, Wt, A, carries, partials);

    int nTask = M * DIMSZ / 8;
    reduce_out_kernel<<<(nTask + 255) / 256, 256, 0, stream>>>(
        partials, bC, (float*)d_out, nTask);
}

// Round 15
// 143.349 us; speedup vs baseline: 1.6226x; 1.0281x over previous
//
#include <hip/hip_runtime.h>
#include <hip/hip_bf16.h>

#define DIMSZ 256
#define HID 4096
#define BATCH 4
#define SEQ 2048
#define NCH 64      // chunks per sequence (carry granularity)
#define CLEN 32     // chunk length
#define SPLITK2 4   // K-splits for fused GEMM2
#define KCHUNK (HID / SPLITK2)   // 1024 channels per block
#define BM2 32      // timesteps per fused-GEMM2 block (= 1 chunk)

typedef __bf16 bf16_t;
typedef __bf16 bf16x8 __attribute__((ext_vector_type(8)));
typedef float  f32x4  __attribute__((ext_vector_type(4)));

__device__ __forceinline__ float sigmoidf_dev(float x) {
    return 1.0f / (1.0f + __expf(-x));
}

// async global->LDS, 16B/lane. LDS dest = wave-uniform base + lane*16.
__device__ __forceinline__ void load_lds16(const bf16_t* g, bf16_t* l) {
    __builtin_amdgcn_global_load_lds(
        (const __attribute__((address_space(1))) void*)g,
        (__attribute__((address_space(3))) void*)l,
        16, 0, 0);
}

__device__ __forceinline__ bf16x8 cvt8(const float* p) {
    bf16x8 o;
    #pragma unroll
    for (int j = 0; j < 8; j++) o[j] = (bf16_t)p[j];
    return o;
}

// ---------------- prep: fused fp32->bf16 convert + MFMA-frag swizzle ----------------
__global__ void prep_kernel(const float* __restrict__ x,
                            const float* __restrict__ WB,
                            const float* __restrict__ WC,
                            bf16_t* __restrict__ xt,
                            bf16_t* __restrict__ WBt,
                            bf16_t* __restrict__ Wt) {
    int i = blockIdx.x * blockDim.x + threadIdx.x;   // 524288
    if (i < 262144) {                                // xt
        int lane = i & 63, m16 = (i >> 6) & 511, ks = i >> 15;
        int row = m16 * 16 + (lane & 15);
        int k   = ks * 32 + (lane >> 4) * 8;
        *(bf16x8*)&xt[(size_t)i * 8] = cvt8(&x[(size_t)row * DIMSZ + k]);
    } else if (i < 393216) {                         // WBt
        int j = i - 262144;
        int lane = j & 63, n16 = (j >> 6) & 255, ks = j >> 14;
        int row = n16 * 16 + (lane & 15);
        int k   = ks * 32 + (lane >> 4) * 8;
        *(bf16x8*)&WBt[(size_t)j * 8] = cvt8(&WB[(size_t)row * DIMSZ + k]);
    } else {                                         // Wt
        int j = i - 393216;
        int lane = j & 63, g = (j >> 6) & 15, ks = j >> 10;
        int row = g * 16 + (lane & 15);
        int k   = ks * 32 + (lane >> 4) * 8;
        *(bf16x8*)&Wt[(size_t)j * 8] = cvt8(&WC[(size_t)row * HID + k]);
    }
}

// ---------------- GEMM1 fused: b = x@WB^T + bB (bf16), + per-chunk totals ----------------
__global__ __launch_bounds__(256)
void gemm1_fused(const bf16_t* __restrict__ xt, const bf16_t* __restrict__ WBt,
                 const float* __restrict__ bias, const float* __restrict__ Adecay,
                 bf16_t* __restrict__ Cg, float* __restrict__ totals)
{
    constexpr int N = HID;
    constexpr int LDTILE = 136;
    __shared__ bf16_t tile[128 * LDTILE];   // 34 KB

    const int tid = threadIdx.x, wave = tid >> 6, lane = tid & 63;
    const int wm = wave >> 1, wn = wave & 1, q = lane >> 4, r16 = lane & 15;
    const int mBase = blockIdx.x * 128, nBase = blockIdx.y * 128;
    const int m16Base = blockIdx.x * 8 + wm * 4;
    const int n16Base = blockIdx.y * 8 + wn * 4;

    f32x4 acc[4][4] = {};

    #pragma unroll 2
    for (int ks = 0; ks < 8; ks++) {
        bf16x8 af[4], bfr[4];
        #pragma unroll
        for (int mt = 0; mt < 4; mt++)
            af[mt] = *(const bf16x8*)&xt[(((size_t)ks * 512 + m16Base + mt) * 64 + lane) * 8];
        #pragma unroll
        for (int nt = 0; nt < 4; nt++)
            bfr[nt] = *(const bf16x8*)&WBt[(((size_t)ks * 256 + n16Base + nt) * 64 + lane) * 8];
        #pragma unroll
        for (int mt = 0; mt < 4; mt++)
            #pragma unroll
            for (int nt = 0; nt < 4; nt++)
                acc[mt][nt] = __builtin_amdgcn_mfma_f32_16x16x32_bf16(
                    af[mt], bfr[nt], acc[mt][nt], 0, 0, 0);
    }

    // acc (+bias) -> LDS tile
    #pragma unroll
    for (int nt = 0; nt < 4; nt++) {
        const int chl = wn * 64 + nt * 16 + r16;
        const float bv = bias[nBase + chl];
        #pragma unroll
        for (int mt = 0; mt < 4; mt++) {
            const int t0 = wm * 64 + mt * 16 + q * 4;
            #pragma unroll
            for (int rg = 0; rg < 4; rg++)
                tile[(t0 + rg) * LDTILE + chl] = (bf16_t)(acc[mt][nt][rg] + bv);
        }
    }
    __syncthreads();

    // coalesced writeback: 8 passes x (16 rows x 128 ch)
    #pragma unroll
    for (int p = 0; p < 8; p++) {
        const int t = p * 16 + (tid >> 4);
        const int ch8 = (tid & 15) << 3;
        *(bf16x8*)&Cg[(size_t)(mBase + t) * N + nBase + ch8] =
            *(const bf16x8*)&tile[t * LDTILE + ch8];
    }

    // chunk totals: 128 channels x 4 chunks, register-batched loads
    #pragma unroll
    for (int t = 0; t < 2; t++) {
        int task = tid + t * 256;
        int ch = task & 127, ck = task >> 7;
        float a = sigmoidf_dev(Adecay[nBase + ch]);
        float v[CLEN];
        #pragma unroll
        for (int i = 0; i < CLEN; i++)
            v[i] = (float)tile[(ck * CLEN + i) * LDTILE + ch];
        float tot = 0.f;
        #pragma unroll
        for (int i = 0; i < CLEN; i++)
            tot = a * tot + v[i];
        int batch = mBase >> 11;
        int cg = ((mBase & 2047) >> 5) + ck;
        totals[(size_t)(batch * NCH + cg) * HID + nBase + ch] = tot;
    }
}

// ---------------- scan over chunk carries, register-batched ----------------
// The 64 totals loads are independent; only the FMA chain is serial. Load all
// 64 up front (one s_waitcnt), then chain in registers — vs 64 serial
// ~300-cyc dependent loads (the same false-chain r14 removed from gemm2).
__global__ void scan_carries_kernel(const float* __restrict__ totals,
                                    const float* __restrict__ Adecay,
                                    float* __restrict__ carries)
{
    int gid = blockIdx.x * 64 + threadIdx.x;   // BATCH*HID
    int ch    = gid & (HID - 1);
    int batch = gid >> 12;
    float a = sigmoidf_dev(Adecay[ch]);
    float aC = a;
    #pragma unroll
    for (int i = 0; i < 5; i++) aC *= aC;      // a^32

    float v[NCH];
    #pragma unroll
    for (int c = 0; c < NCH; c++)
        v[c] = totals[(size_t)(batch * NCH + c) * HID + ch];

    float carry = 0.f;
    #pragma unroll
    for (int c = 0; c < NCH; c++) {
        carries[(size_t)(batch * NCH + c) * HID + ch] = carry;
        carry = aC * carry + v[c];
    }
}

// ---------------- fused scan + GEMM2 split-K (BM2=32, bf16 partials) ----------------
// Per block: 32 timesteps (= 1 chunk) x N=256 x 1024-ch K-slice, 4 slabs of 256 ch.
// hs (16.9 KB) doubles as the bf16 epilogue tile after the last slab.
__global__ __launch_bounds__(256)
void gemm2_fused(const bf16_t* __restrict__ bv, const bf16_t* __restrict__ Wt,
                 const float* __restrict__ Adecay, const float* __restrict__ carries,
                 bf16_t* __restrict__ P)
{
    constexpr int CKSTRIDE = BM2 * 32 + 32;    // 1056: +64B stagger between ck slabs
    __shared__ bf16_t hs[8 * CKSTRIDE];        // 16.9 KB (== 32x264 epilogue tile)

    const int tid = threadIdx.x, wave = tid >> 6, lane = tid & 63;
    const int q = lane >> 4, r16 = lane & 15;
    const int mBase = blockIdx.x * BM2;
    const int kBase = blockIdx.y * KCHUNK;
    const int batch = mBase >> 11;
    const int chunk0 = (mBase & 2047) >> 5;

    f32x4 acc[2][4] = {};

    for (int s = 0; s < KCHUNK / 256; s++) {
        const int chSlab = kBase + s * 256;

        if (s > 0) __syncthreads();   // all waves done reading hs before DMA lands

        // stage b-slab -> hs: 16 wave-loads total, 4 per wave
        #pragma unroll
        for (int i = 0; i < 4; i++) {
            int ck = wave * 2 + (i >> 1);
            int g  = i & 1;
            load_lds16(&bv[(size_t)(mBase + g * 16 + (lane >> 2)) * HID
                           + chSlab + ck * 32 + ((lane & 3) << 3)],
                       &hs[ck * CKSTRIDE + g * 512]);
        }

        // seed (coalesced load, issued during staging)
        const int ck = tid >> 5, ch = tid & 31;
        const int c = chSlab + ck * 32 + ch;
        const float a = sigmoidf_dev(Adecay[c]);
        float st = carries[(size_t)(batch * NCH + chunk0) * HID + c];

        __syncthreads();   // staging drained

        // in-place scan, register-batched
        {
            bf16_t* hp = &hs[ck * CKSTRIDE + ch];
            float v[BM2];
            #pragma unroll
            for (int t = 0; t < BM2; t++)
                v[t] = (float)hp[t * 32];
            #pragma unroll
            for (int t = 0; t < BM2; t++) {
                st = a * st + v[t];
                v[t] = st;
            }
            #pragma unroll
            for (int t = 0; t < BM2; t++)
                hp[t * 32] = (bf16_t)v[t];
        }
        __syncthreads();   // hs = h, visible to all waves

        // barrier-free MFMA k-steps; B-frags direct from swizzled global
        const int ksBase = (kBase >> 5) + s * 8;
        #pragma unroll 2
        for (int cki = 0; cki < 8; cki++) {
            bf16x8 af[2], bfr[4];
            #pragma unroll
            for (int nt = 0; nt < 4; nt++)
                bfr[nt] = *(const bf16x8*)&Wt[
                    (((size_t)(ksBase + cki) * 16 + wave * 4 + nt) * 64 + lane) * 8];
            #pragma unroll
            for (int mt = 0; mt < 2; mt++)
                af[mt] = *(const bf16x8*)&hs[cki * CKSTRIDE + (mt * 16 + r16) * 32 + q * 8];
            #pragma unroll
            for (int mt = 0; mt < 2; mt++)
                #pragma unroll
                for (int nt = 0; nt < 4; nt++)
                    acc[mt][nt] = __builtin_amdgcn_mfma_f32_16x16x32_bf16(
                        af[mt], bfr[nt], acc[mt][nt], 0, 0, 0);
        }
    }

    // epilogue: acc -> bf16 LDS tile (reuse hs) -> coalesced 16B partial stores
    __syncthreads();                           // all waves done reading hs
    #pragma unroll
    for (int nt = 0; nt < 4; nt++) {
        const int col = wave * 64 + nt * 16 + r16;
        #pragma unroll
        for (int mt = 0; mt < 2; mt++)
            #pragma unroll
            for (int rg = 0; rg < 4; rg++)
                hs[(mt * 16 + q * 4 + rg) * 264 + col] = (bf16_t)acc[mt][nt][rg];
    }
    __syncthreads();

    bf16_t* Pb = P + (size_t)blockIdx.y * (BATCH * SEQ) * DIMSZ;
    #pragma unroll
    for (int p = 0; p < 4; p++) {
        int task = p * 256 + tid;
        int r = task >> 5, g8 = (task & 31) << 3;
        *(bf16x8*)&Pb[(size_t)(mBase + r) * DIMSZ + g8] =
            *(const bf16x8*)&hs[r * 264 + g8];
    }
}

// ---------------- reduce bf16 partials + bias -> fp32 d_out ----------------
__global__ void reduce_out_kernel(const bf16_t* __restrict__ P,
                                  const float* __restrict__ bias,
                                  float* __restrict__ out, int nTask) {
    int i = blockIdx.x * blockDim.x + threadIdx.x;   // M*256/8
    if (i >= nTask) return;
    int n8 = (i & 31) << 3;
    size_t off = (size_t)i * 8;
    float v[8];
    #pragma unroll
    for (int j = 0; j < 8; j++) v[j] = bias[n8 + j];
    #pragma unroll
    for (int sp = 0; sp < SPLITK2; sp++) {
        bf16x8 p = *(const bf16x8*)&P[(size_t)sp * (BATCH * SEQ) * DIMSZ + off];
        #pragma unroll
        for (int j = 0; j < 8; j++) v[j] += (float)p[j];
    }
    float4* o4 = (float4*)&out[off];
    o4[0] = make_float4(v[0], v[1], v[2], v[3]);
    o4[1] = make_float4(v[4], v[5], v[6], v[7]);
}

extern "C" void kernel_launch(void* const* d_in, const int* in_sizes, int n_in,
                              void* d_out, int out_size, void* d_ws, size_t ws_size,
                              hipStream_t stream)
{
    const float* x  = (const float*)d_in[0];
    const float* WB = (const float*)d_in[1];
    const float* bB = (const float*)d_in[2];
    const float* WC = (const float*)d_in[3];
    const float* bC = (const float*)d_in[4];
    const float* A  = (const float*)d_in[5];

    char* ws = (char*)d_ws;
    size_t off = 0;
    bf16_t* xt   = (bf16_t*)(ws + off); off += (size_t)BATCH * SEQ * DIMSZ * 2;  // 4 MB
    bf16_t* WBt  = (bf16_t*)(ws + off); off += (size_t)HID * DIMSZ * 2;          // 2 MB
    bf16_t* Wt   = (bf16_t*)(ws + off); off += (size_t)DIMSZ * HID * 2;          // 2 MB
    bf16_t* bbuf = (bf16_t*)(ws + off); off += (size_t)BATCH * SEQ * HID * 2;    // 64 MB
    bf16_t* partials = (bf16_t*)(ws + off); off += (size_t)SPLITK2 * BATCH * SEQ * DIMSZ * 2; // 16.75 MB
    float* totals   = (float*)(ws + off); off += (size_t)BATCH * NCH * HID * 4;
    float* carries  = (float*)(ws + off); off += (size_t)BATCH * NCH * HID * 4;

    const int M = BATCH * SEQ;   // 8192

    prep_kernel<<<2048, 256, 0, stream>>>(x, WB, WC, xt, WBt, Wt);

    dim3 g1(M / 128, HID / 128);
    gemm1_fused<<<g1, 256, 0, stream>>>(xt, WBt, bB, A, bbuf, totals);

    scan_carries_kernel<<<256, 64, 0, stream>>>(totals, A, carries);

    dim3 g2(M / BM2, SPLITK2);
    gemm2_fused<<<g2, 256, 0, stream>>>(bbuf, Wt, A, carries, partials);

    int nTask = M * DIMSZ / 8;
    reduce_out_kernel<<<(nTask + 255) / 256, 256, 0, stream>>>(
        partials, bC, (float*)d_out, nTask);
}